// Round 1
// baseline (399.769 us; speedup 1.0000x reference)
//
#include <hip/hip_runtime.h>
#include <math.h>

#define N 8
#define DIM 64
#define H 256
#define W 256
#define K 3
#define EPS 1e-5f
#define TH 32   // rows per conv block; LDS = (TH+2)*W*4 = 34816 B -> 4 blocks/CU

// ---------------- Kernel 1: global average pool per (n,c) plane ----------------
__global__ void gap_kernel(const float* __restrict__ x, float* __restrict__ gap) {
    const int plane = blockIdx.x;                 // n*DIM + c, 512 planes
    const float4* p4 = (const float4*)(x + (size_t)plane * (H * W));
    const int tid = threadIdx.x;                  // 256 threads
    float s = 0.f;
    // H*W/4 = 16384 float4 per plane; 64 per thread, coalesced
    #pragma unroll 4
    for (int i = tid; i < (H * W) / 4; i += 256) {
        float4 v = p4[i];
        s += (v.x + v.y) + (v.z + v.w);
    }
    __shared__ float red[256];
    red[tid] = s;
    __syncthreads();
    for (int off = 128; off > 0; off >>= 1) {
        if (tid < off) red[tid] += red[tid + off];
        __syncthreads();
    }
    if (tid == 0) gap[plane] = red[0] * (1.0f / (H * W));
}

// ---------------- Kernel 2: taps = tanh(BN(gap @ w.T)) for both branches ----------------
__global__ void taps_kernel(const float* __restrict__ gap,
                            const float* __restrict__ wH, const float* __restrict__ gH,
                            const float* __restrict__ bH, const float* __restrict__ mH,
                            const float* __restrict__ vH,
                            const float* __restrict__ wW, const float* __restrict__ gW,
                            const float* __restrict__ bW, const float* __restrict__ mW,
                            const float* __restrict__ vW,
                            float* __restrict__ taps) {
    int idx = blockIdx.x * blockDim.x + threadIdx.x;     // [0, 2*N*DIM*K)
    if (idx >= 2 * N * DIM * K) return;
    const int branch = idx / (N * DIM * K);
    const int rem    = idx % (N * DIM * K);
    const int n      = rem / (DIM * K);
    const int j      = rem % (DIM * K);                  // j = c*K + k
    const float* w = branch ? wW : wH;
    const float* g = branch ? gW : gH;
    const float* b = branch ? bW : bH;
    const float* m = branch ? mW : mH;
    const float* v = branch ? vW : vH;
    const float* grow = gap + n * DIM;
    const float* wrow = w + (size_t)j * DIM;
    float acc = 0.f;
    #pragma unroll
    for (int d = 0; d < DIM; d++) acc += grow[d] * wrow[d];
    float f = (acc - m[j]) * (g[j] * rsqrtf(v[j] + EPS)) + b[j];
    taps[idx] = tanhf(f);
}

// ---------------- Kernel 3: fused dual-strip depthwise conv ----------------
// Block: 256 threads = one column each; processes TH rows of one (n,c) plane.
// Computes BOTH the horizontal (1,K) and vertical (K,1) outputs from one LDS tile.
__global__ __launch_bounds__(256) void conv_kernel(const float* __restrict__ x,
                                                   const float* __restrict__ taps,
                                                   float* __restrict__ out) {
    __shared__ float tile[TH + 2][W];
    const int plane = blockIdx.y;                 // n*DIM + c
    const int n = plane / DIM;
    const int c = plane % DIM;
    const int h0 = blockIdx.x * TH;
    const int w = threadIdx.x;                    // 0..255

    const float* xp = x + (size_t)plane * (H * W);

    // Stage TH+2 rows (h0-1 .. h0+TH) with reflect padding at plane edges.
    #pragma unroll
    for (int r = 0; r < TH + 2; r++) {
        int hh = h0 - 1 + r;
        if (hh < 0) hh = -hh;                     // -1 -> 1 (reflect, edge excluded)
        if (hh >= H) hh = 2 * H - 2 - hh;         //  H -> H-2
        tile[r][w] = xp[hh * W + w];
    }
    __syncthreads();

    // Taps: layout taps[branch][n][c*K + k]
    const float* tH = taps + (n * DIM + c) * K;
    const float* tW = taps + N * DIM * K + (n * DIM + c) * K;
    const float tH0 = tH[0], tH1 = tH[1], tH2 = tH[2];
    const float tW0 = tW[0], tW1 = tW[1], tW2 = tW[2];

    // Output: (N, 2*DIM, H, W); branch0 channels [0,DIM), branch1 [DIM,2*DIM)
    float* out1 = out + (((size_t)n * 2 * DIM + c) * H + h0) * W;
    float* out2 = out + (((size_t)n * 2 * DIM + DIM + c) * H + h0) * W;

    const int wm = (w == 0) ? 1 : w - 1;          // reflect in W
    const int wp = (w == W - 1) ? W - 2 : w + 1;

    #pragma unroll 4
    for (int r = 0; r < TH; r++) {
        const float xc = tile[r + 1][w];
        const float o1 = tile[r + 1][wm] * tH0 + xc * tH1 + tile[r + 1][wp] * tH2;
        const float o2 = tile[r][w] * tW0 + xc * tW1 + tile[r + 2][w] * tW2;
        out1[r * W + w] = o1;
        out2[r * W + w] = o2;
    }
}

extern "C" void kernel_launch(void* const* d_in, const int* in_sizes, int n_in,
                              void* d_out, int out_size, void* d_ws, size_t ws_size,
                              hipStream_t stream) {
    const float* x  = (const float*)d_in[0];
    const float* wH = (const float*)d_in[1];
    const float* gH = (const float*)d_in[2];
    const float* bH = (const float*)d_in[3];
    const float* mH = (const float*)d_in[4];
    const float* vH = (const float*)d_in[5];
    const float* wW = (const float*)d_in[6];
    const float* gW = (const float*)d_in[7];
    const float* bW = (const float*)d_in[8];
    const float* mW = (const float*)d_in[9];
    const float* vW = (const float*)d_in[10];
    float* out = (float*)d_out;

    float* gap  = (float*)d_ws;                   // N*DIM floats
    float* taps = gap + N * DIM;                  // 2*N*DIM*K floats

    gap_kernel<<<N * DIM, 256, 0, stream>>>(x, gap);

    const int ntaps = 2 * N * DIM * K;
    taps_kernel<<<(ntaps + 255) / 256, 256, 0, stream>>>(gap, wH, gH, bH, mH, vH,
                                                         wW, gW, bW, mW, vW, taps);

    dim3 grid(H / TH, N * DIM);
    conv_kernel<<<grid, 256, 0, stream>>>(x, taps, out);
}